// Round 2
// baseline (439.922 us; speedup 1.0000x reference)
//
#include <hip/hip_runtime.h>
#include <cstdint>

#define N_TOK 16384
#define HDIM 1024
#define NEXPERTS 8
#define VOCABM1 50256
#define BM 128
#define BN 128
#define BK 32
#define MAX_TILES 136          // 16384/128 + 8 (worst-case padding); 136 = 17*8
#define MPAD (MAX_TILES * BM)  // 17408

typedef __attribute__((ext_vector_type(8))) __bf16 bf16x8;
typedef __attribute__((ext_vector_type(4))) __bf16 bf16x4;
typedef __attribute__((ext_vector_type(2))) __bf16 bf16x2;
typedef __attribute__((ext_vector_type(4))) float f32x4;

__device__ inline void gl_lds16(const void* g, void* l) {
  __builtin_amdgcn_global_load_lds(
      (const __attribute__((address_space(1))) void*)g,
      (__attribute__((address_space(3))) void*)l, 16, 0, 0);
}

__device__ inline int expert_of(int t) {
  t = t < 0 ? 0 : (t > VOCABM1 ? VOCABM1 : t);
  return t & 7;
}

// ---------------- fused routing: histogram + tile table + padded permutation ----------------
__global__ __launch_bounds__(1024) void k_route(const int* __restrict__ tok,
                                                int* __restrict__ perm,
                                                int* __restrict__ tileExpert,
                                                int* __restrict__ numTiles) {
  __shared__ int cnt[NEXPERTS];
  __shared__ int cur[NEXPERTS];
  int tid = threadIdx.x;
  if (tid < NEXPERTS) cnt[tid] = 0;
  __syncthreads();

  int base = tid * 16;
  int4 v[4];
  const int4* t4 = (const int4*)(tok + base);
#pragma unroll
  for (int i = 0; i < 4; ++i) v[i] = t4[i];
  int myE[16];
  int loc[NEXPERTS];
#pragma unroll
  for (int e = 0; e < NEXPERTS; ++e) loc[e] = 0;
#pragma unroll
  for (int i = 0; i < 16; ++i) {
    int e = expert_of(((const int*)v)[i]);
    myE[i] = e;
    ++loc[e];
  }
#pragma unroll
  for (int e = 0; e < NEXPERTS; ++e)
    if (loc[e]) atomicAdd(&cnt[e], loc[e]);
  __syncthreads();

  if (tid == 0) {
    int t = 0;
    for (int e = 0; e < NEXPERTS; ++e) {
      cur[e] = t * BM;  // padded offset doubles as scatter cursor
      int nt = (cnt[e] + BM - 1) / BM;
      for (int i = 0; i < nt; ++i) tileExpert[t++] = e;
    }
    *numTiles = t;
  }
  __syncthreads();

  for (int i = tid; i < MPAD; i += 1024) perm[i] = -1;
  __syncthreads();

#pragma unroll
  for (int i = 0; i < 16; ++i) {
    int pos = atomicAdd(&cur[myE[i]], 1);
    perm[pos] = base + i;
  }
}

// ---------------- merged prep: weight transpose+convert AND x gather+convert (R5) ----------------
// blocks [0,3840): 64x64 weight transpose tiles. blocks [3840,8192): xp[p]=bf16(x[perm[p]]).
__global__ void k_prep(const float* __restrict__ gw, const float* __restrict__ uw,
                       const float* __restrict__ dw, const float* __restrict__ sgw,
                       const float* __restrict__ suw, const float* __restrict__ sdw,
                       __bf16* __restrict__ B1r, __bf16* __restrict__ B2r,
                       __bf16* __restrict__ B1s, __bf16* __restrict__ B2s,
                       const float* __restrict__ x, const int* __restrict__ perm,
                       __bf16* __restrict__ xp) {
  int b = blockIdx.x;
  if (b >= 3840) {  // ---- gather-convert part ----
    int tid = threadIdx.x;
    int p = (b - 3840) * 4 + (tid >> 6);
    int t = perm[p];
    __bf16* dst = xp + (long)p * HDIM;
    int c0 = (tid & 63) * 4;
    if (t < 0) {
      bf16x4 z = {};
#pragma unroll
      for (int it = 0; it < 4; ++it) *(bf16x4*)(dst + c0 + it * 256) = z;
    } else {
      const float* src = x + (long)t * HDIM;
#pragma unroll
      for (int it = 0; it < 4; ++it) {
        float4 v = *(const float4*)(src + c0 + it * 256);
        bf16x4 o = {(__bf16)v.x, (__bf16)v.y, (__bf16)v.z, (__bf16)v.w};
        *(bf16x4*)(dst + c0 + it * 256) = o;
      }
    }
    return;
  }
  // ---- transpose part: src [K][N] fp32 -> dst [rowmap(n)][K] bf16 ----
  const float* src;
  __bf16* dst;
  int K, N, interleave, slot, xt, yt;
  if (b < 2048) {  // gate_w/up_w -> B1r (16-col gate/up interleave)
    slot = b >> 10;
    int r = b & 1023, e = r >> 7, t = r & 127;
    xt = t & 7; yt = t >> 3;
    K = 1024; N = 512; interleave = 1;
    src = (slot ? uw : gw) + (long)e * (1024L * 512);
    dst = B1r + (long)e * (1024L * 1024);
  } else if (b < 3072) {  // down_w -> B2r
    int r = b - 2048, e = r >> 7, t = r & 127;
    xt = t & 15; yt = t >> 4;
    K = 512; N = 1024; interleave = 0; slot = 0;
    src = dw + (long)e * (512L * 1024);
    dst = B2r + (long)e * (1024L * 512);
  } else if (b < 3584) {  // shared gate/up -> B1s
    int r = b - 3072;
    slot = r >> 8;
    int t = r & 255;
    xt = t & 15; yt = t >> 4;
    K = 1024; N = 1024; interleave = 1;
    src = slot ? suw : sgw;
    dst = B1s;
  } else {  // shared down -> B2s
    int t = b - 3584;
    xt = t & 15; yt = t >> 4;
    K = 1024; N = 1024; interleave = 0; slot = 0;
    src = sdw;
    dst = B2s;
  }

  __shared__ float tile[64][65];
  int n0 = xt * 64, k0 = yt * 64;
  int tid = threadIdx.x, tx = tid & 15, ty = tid >> 4;
#pragma unroll
  for (int rr = 0; rr < 64; rr += 16) {
    float4 v = *(const float4*)(src + (long)(k0 + ty + rr) * N + n0 + tx * 4);
    tile[ty + rr][tx * 4 + 0] = v.x;
    tile[ty + rr][tx * 4 + 1] = v.y;
    tile[ty + rr][tx * 4 + 2] = v.z;
    tile[ty + rr][tx * 4 + 3] = v.w;
  }
  __syncthreads();
  int kp = tid & 31, rs = tid >> 5;
#pragma unroll
  for (int rr = 0; rr < 64; rr += 8) {
    int n = n0 + rs + rr;
    int row = interleave ? (((n >> 4) << 5) | (slot << 4) | (n & 15)) : n;
    bf16x2 u = {(__bf16)tile[2 * kp][rs + rr], (__bf16)tile[2 * kp + 1][rs + rr]};
    *(bf16x2*)(dst + (long)row * K + k0 + 2 * kp) = u;
  }
}

// ---------------- fused up-projection GEMM (shared + routed) ----------------
// A = xp [MPAD][1024]. ny<16: B=B1s (shared), out hs; ny>=16: B=B1r[e], out hr.
// R5: flat grid + XCD swizzle (g&7 = XCD under round-robin dispatch).
// R7: epilogue LDS-transpose -> bf16x8 stores (was 32x scalar 2B stores/thread;
//     32B segments -> 128B segments on 53MB of hs/hr traffic). Rotation swizzle
//     (chunk += 16*q mod 64) keeps both LDS phases <=2-way conflicts (free, m136).
__global__ __launch_bounds__(256) void k_up(
    const __bf16* __restrict__ A, const __bf16* __restrict__ B1s,
    const __bf16* __restrict__ B1r, __bf16* __restrict__ hs, __bf16* __restrict__ hr,
    const int* __restrict__ tileExpert, const int* __restrict__ numTiles) {
  int g = blockIdx.x;
  int s = g >> 3;
  int mTile = (s / 24) * 8 + (g & 7);
  int ny = s % 24;
  if (mTile >= *numTiles) return;
  bool sh = (ny < 16);
  const __bf16* Bb = sh ? (B1s + (long)ny * BN * 1024)
                        : (B1r + (long)tileExpert[mTile] * (1024L * 1024) +
                           (long)(ny - 16) * BN * 1024);

  __shared__ __attribute__((aligned(16))) __bf16 smem[BM * BK + BN * BK];  // 16 KB
  __bf16* As = smem;
  __bf16* Bs = smem + BM * BK;

  int tid = threadIdx.x, lane = tid & 63, wave = tid >> 6;
  int wRow = (wave >> 1) * 64, wCol = (wave & 1) * 64;
  int mBase = mTile * BM;

  int rloc = lane >> 2;
  int cg = ((lane & 3) ^ ((lane >> 3) & 3)) * 8;  // swizzled global chunk (elements)
  const __bf16* aP0 = A + (long)(mBase + wave * 32 + rloc) * 1024 + cg;
  const __bf16* aP1 = aP0 + 16 * 1024;
  const __bf16* bP0 = Bb + (long)(wave * 32 + rloc) * 1024 + cg;
  const __bf16* bP1 = bP0 + 16 * 1024;
  __bf16* lA0 = &As[(wave * 32) * BK];
  __bf16* lA1 = &As[(wave * 32 + 16) * BK];
  __bf16* lB0 = &Bs[(wave * 32) * BK];
  __bf16* lB1 = &Bs[(wave * 32 + 16) * BK];

  int m = lane & 15;
  int qs = ((lane >> 4) ^ ((lane >> 1) & 3)) * 8;  // swizzled read chunk (elements)
  const int aBase = (wRow + m) * BK + qs;
  const int bBase = (wCol + m) * BK + qs;

  f32x4 acc[4][4] = {};
  for (int k0 = 0; k0 < 1024; k0 += BK) {
    gl_lds16(aP0 + k0, lA0);
    gl_lds16(aP1 + k0, lA1);
    gl_lds16(bP0 + k0, lB0);
    gl_lds16(bP1 + k0, lB1);
    __syncthreads();
    bf16x8 af[4], bf[4];
#pragma unroll
    for (int i = 0; i < 4; ++i) af[i] = *(const bf16x8*)&As[aBase + i * 16 * BK];
#pragma unroll
    for (int j = 0; j < 4; ++j) bf[j] = *(const bf16x8*)&Bs[bBase + j * 16 * BK];
#pragma unroll
    for (int i = 0; i < 4; ++i)
#pragma unroll
      for (int j = 0; j < 4; ++j)
        acc[i][j] = __builtin_amdgcn_mfma_f32_16x16x32_bf16(af[i], bf[j], acc[i][j], 0, 0, 0);
    __syncthreads();
  }

  // ---- R7 epilogue: SiLU*up -> wave-pair [64][64] LDS scratch -> 16B stores ----
  // Wave-pair p = wave>>1 owns rows [p*64, p*64+64) x cols [colBase, colBase+64).
  // C/D frag: col = lane&15 (+jp*16 +(wave&1)*32), row = i*16 + (lane>>4)*4 + reg.
  __bf16* scr = smem + (wave >> 1) * 4096;  // 64*64 bf16 per pair (2 pairs = 16 KB)
  int q = lane >> 4, c = lane & 15;
  int w1 = (wave & 1) * 32;
#pragma unroll
  for (int i = 0; i < 4; ++i) {
#pragma unroll
    for (int jp = 0; jp < 2; ++jp) {
      f32x4 g2 = acc[i][2 * jp], u = acc[i][2 * jp + 1];
#pragma unroll
      for (int r = 0; r < 4; ++r) {
        float gv = g2[r];
        float sv = gv / (1.f + __expf(-gv)) * u[r];
        int lr = i * 16 + q * 4 + r;  // (lr>>2)&3 == q
        scr[lr * 64 + ((w1 + jp * 16 + c + q * 16) & 63)] = (__bf16)sv;
      }
    }
  }
  __syncthreads();
  __bf16* dst = sh ? hs : hr;
  int ldh = sh ? 1024 : 512;
  int colBase = sh ? ny * 64 : (ny - 16) * 64;
  int rl = lane >> 3, ch = (lane & 7) * 8;
  long rowBase = mBase + (wave >> 1) * 64;
#pragma unroll
  for (int it = 0; it < 8; ++it) {
    int lr = rl + it * 8;
    bf16x8 v = *(const bf16x8*)&scr[lr * 64 + ((ch + ((lr >> 2) & 3) * 16) & 63)];
    *(bf16x8*)(dst + (rowBase + lr) * ldh + colBase + ch) = v;
  }
}

// ---------------- fused down-projection GEMM: out[perm[p]] = hs[p]*B2s + hr[p]*B2r[e] ----------------
__global__ __launch_bounds__(256) void k_down(
    const __bf16* __restrict__ hs, const __bf16* __restrict__ hr,
    const __bf16* __restrict__ B2s, const __bf16* __restrict__ B2r,
    float* __restrict__ out, const int* __restrict__ perm,
    const int* __restrict__ tileExpert, const int* __restrict__ numTiles) {
  int g = blockIdx.x;  // R5: XCD swizzle (see k_up)
  int s = g >> 3;
  int mTile = (s / 8) * 8 + (g & 7);
  int nTile = s % 8;
  if (mTile >= *numTiles) return;
  int e = tileExpert[mTile];

  __shared__ __bf16 As[BM * BK];
  __shared__ __bf16 Bs[BN * BK];

  int tid = threadIdx.x, lane = tid & 63, wave = tid >> 6;
  int wRow = (wave >> 1) * 64, wCol = (wave & 1) * 64;
  int mBase = mTile * BM;

  int rloc = lane >> 2;
  int cg = ((lane & 3) ^ ((lane >> 3) & 3)) * 8;
  __bf16* lA0 = &As[(wave * 32) * BK];
  __bf16* lA1 = &As[(wave * 32 + 16) * BK];
  __bf16* lB0 = &Bs[(wave * 32) * BK];
  __bf16* lB1 = &Bs[(wave * 32 + 16) * BK];

  int m = lane & 15;
  int qs = ((lane >> 4) ^ ((lane >> 1) & 3)) * 8;
  const int aBase = (wRow + m) * BK + qs;
  const int bBase = (wCol + m) * BK + qs;

  f32x4 acc[4][4] = {};

  // phase 1: shared down (K=1024)
  {
    const __bf16* aP0 = hs + (long)(mBase + wave * 32 + rloc) * 1024 + cg;
    const __bf16* aP1 = aP0 + 16 * 1024;
    const __bf16* bP0 = B2s + (long)(nTile * BN + wave * 32 + rloc) * 1024 + cg;
    const __bf16* bP1 = bP0 + 16 * 1024;
    for (int k0 = 0; k0 < 1024; k0 += BK) {
      gl_lds16(aP0 + k0, lA0);
      gl_lds16(aP1 + k0, lA1);
      gl_lds16(bP0 + k0, lB0);
      gl_lds16(bP1 + k0, lB1);
      __syncthreads();
      bf16x8 af[4], bf[4];
#pragma unroll
      for (int i = 0; i < 4; ++i) af[i] = *(const bf16x8*)&As[aBase + i * 16 * BK];
#pragma unroll
      for (int j = 0; j < 4; ++j) bf[j] = *(const bf16x8*)&Bs[bBase + j * 16 * BK];
#pragma unroll
      for (int i = 0; i < 4; ++i)
#pragma unroll
        for (int j = 0; j < 4; ++j)
          acc[i][j] = __builtin_amdgcn_mfma_f32_16x16x32_bf16(af[i], bf[j], acc[i][j], 0, 0, 0);
      __syncthreads();
    }
  }
  // phase 2: routed down (K=512)
  {
    const __bf16* aP0 = hr + (long)(mBase + wave * 32 + rloc) * 512 + cg;
    const __bf16* aP1 = aP0 + 16 * 512;
    const __bf16* bP0 = B2r + (long)e * (1024L * 512) +
                        (long)(nTile * BN + wave * 32 + rloc) * 512 + cg;
    const __bf16* bP1 = bP0 + 16 * 512;
    for (int k0 = 0; k0 < 512; k0 += BK) {
      gl_lds16(aP0 + k0, lA0);
      gl_lds16(aP1 + k0, lA1);
      gl_lds16(bP0 + k0, lB0);
      gl_lds16(bP1 + k0, lB1);
      __syncthreads();
      bf16x8 af[4], bf[4];
#pragma unroll
      for (int i = 0; i < 4; ++i) af[i] = *(const bf16x8*)&As[aBase + i * 16 * BK];
#pragma unroll
      for (int j = 0; j < 4; ++j) bf[j] = *(const bf16x8*)&Bs[bBase + j * 16 * BK];
#pragma unroll
      for (int i = 0; i < 4; ++i)
#pragma unroll
        for (int j = 0; j < 4; ++j)
          acc[i][j] = __builtin_amdgcn_mfma_f32_16x16x32_bf16(af[i], bf[j], acc[i][j], 0, 0, 0);
      __syncthreads();
    }
  }

  int q = lane >> 4, c = lane & 15;
#pragma unroll
  for (int i = 0; i < 4; ++i) {
    int rowLoc = wRow + i * 16 + q * 4;
#pragma unroll
    for (int r = 0; r < 4; ++r) {
      int tok = perm[mBase + rowLoc + r];
      if (tok >= 0) {
        float* op = out + (long)tok * 1024 + nTile * BN + wCol + c;
#pragma unroll
        for (int j = 0; j < 4; ++j) op[j * 16] = acc[i][j][r];
      }
    }
  }
}

// ---------------- launch ----------------
extern "C" void kernel_launch(void* const* d_in, const int* in_sizes, int n_in,
                              void* d_out, int out_size, void* d_ws, size_t ws_size,
                              hipStream_t stream) {
  const float* x = (const float*)d_in[0];
  const int* tok = (const int*)d_in[1];
  const float* gate_w = (const float*)d_in[2];
  const float* up_w = (const float*)d_in[3];
  const float* down_w = (const float*)d_in[4];
  const float* sgw = (const float*)d_in[5];
  const float* suw = (const float*)d_in[6];
  const float* sdw = (const float*)d_in[7];
  float* out = (float*)d_out;

  char* ws = (char*)d_ws;
  size_t off = 0;
  auto alloc = [&](size_t bytes) {
    void* p = ws + off;
    off = (off + bytes + 255) & ~(size_t)255;
    return p;
  };
  int* ctrl = (int*)alloc(1024);  // numTiles[1] tileExpert[136]
  int* numTiles = ctrl;
  int* tileExpert = ctrl + 8;
  int* perm = (int*)alloc((size_t)MPAD * 4);
  __bf16* xp = (__bf16*)alloc((size_t)MPAD * HDIM * 2);
  __bf16* B1r = (__bf16*)alloc((size_t)NEXPERTS * 1024 * 1024 * 2);  // gate|up interleaved
  __bf16* B2r = (__bf16*)alloc((size_t)NEXPERTS * 1024 * 512 * 2);
  __bf16* B1s = (__bf16*)alloc((size_t)2048 * 1024 * 2);
  __bf16* B2s = (__bf16*)alloc((size_t)1024 * 1024 * 2);
  __bf16* hs = (__bf16*)alloc((size_t)MPAD * 1024 * 2);
  __bf16* hr = (__bf16*)alloc((size_t)MPAD * 512 * 2);
  (void)ws_size;  // ~121 MB used

  // 4 dispatches total (R5; was 5)
  k_route<<<1, 1024, 0, stream>>>(tok, perm, tileExpert, numTiles);
  k_prep<<<3840 + MPAD / 4, 256, 0, stream>>>(gate_w, up_w, down_w, sgw, suw, sdw, B1r, B2r,
                                              B1s, B2s, x, perm, xp);
  k_up<<<MAX_TILES * 24, 256, 0, stream>>>(xp, B1s, B1r, hs, hr, tileExpert, numTiles);
  k_down<<<MAX_TILES * 8, 256, 0, stream>>>(hs, hr, B2s, B2r, out, perm, tileExpert,
                                            numTiles);
}

// Round 3
// 398.567 us; speedup vs baseline: 1.1038x; 1.1038x over previous
//
#include <hip/hip_runtime.h>
#include <cstdint>

#define N_TOK 16384
#define HDIM 1024
#define NEXPERTS 8
#define VOCABM1 50256
#define BM 128
#define BN 128
#define BK 64                  // R8: was 32 — halves barrier-drain count per block
#define MAX_TILES 136          // 16384/128 + 8 (worst-case padding); 136 = 17*8
#define MPAD (MAX_TILES * BM)  // 17408

typedef __attribute__((ext_vector_type(8))) __bf16 bf16x8;
typedef __attribute__((ext_vector_type(4))) __bf16 bf16x4;
typedef __attribute__((ext_vector_type(2))) __bf16 bf16x2;
typedef __attribute__((ext_vector_type(4))) float f32x4;

__device__ inline void gl_lds16(const void* g, void* l) {
  __builtin_amdgcn_global_load_lds(
      (const __attribute__((address_space(1))) void*)g,
      (__attribute__((address_space(3))) void*)l, 16, 0, 0);
}

__device__ inline int expert_of(int t) {
  t = t < 0 ? 0 : (t > VOCABM1 ? VOCABM1 : t);
  return t & 7;
}

// ---------------- fused routing: histogram + tile table + padded permutation ----------------
__global__ __launch_bounds__(1024) void k_route(const int* __restrict__ tok,
                                                int* __restrict__ perm,
                                                int* __restrict__ tileExpert,
                                                int* __restrict__ numTiles) {
  __shared__ int cnt[NEXPERTS];
  __shared__ int cur[NEXPERTS];
  int tid = threadIdx.x;
  if (tid < NEXPERTS) cnt[tid] = 0;
  __syncthreads();

  int base = tid * 16;
  int4 v[4];
  const int4* t4 = (const int4*)(tok + base);
#pragma unroll
  for (int i = 0; i < 4; ++i) v[i] = t4[i];
  int myE[16];
  int loc[NEXPERTS];
#pragma unroll
  for (int e = 0; e < NEXPERTS; ++e) loc[e] = 0;
#pragma unroll
  for (int i = 0; i < 16; ++i) {
    int e = expert_of(((const int*)v)[i]);
    myE[i] = e;
    ++loc[e];
  }
#pragma unroll
  for (int e = 0; e < NEXPERTS; ++e)
    if (loc[e]) atomicAdd(&cnt[e], loc[e]);
  __syncthreads();

  if (tid == 0) {
    int t = 0;
    for (int e = 0; e < NEXPERTS; ++e) {
      cur[e] = t * BM;  // padded offset doubles as scatter cursor
      int nt = (cnt[e] + BM - 1) / BM;
      for (int i = 0; i < nt; ++i) tileExpert[t++] = e;
    }
    *numTiles = t;
  }
  __syncthreads();

  for (int i = tid; i < MPAD; i += 1024) perm[i] = -1;
  __syncthreads();

#pragma unroll
  for (int i = 0; i < 16; ++i) {
    int pos = atomicAdd(&cur[myE[i]], 1);
    perm[pos] = base + i;
  }
}

// ---------------- merged prep: weight transpose+convert AND x gather+convert ----------------
__global__ void k_prep(const float* __restrict__ gw, const float* __restrict__ uw,
                       const float* __restrict__ dw, const float* __restrict__ sgw,
                       const float* __restrict__ suw, const float* __restrict__ sdw,
                       __bf16* __restrict__ B1r, __bf16* __restrict__ B2r,
                       __bf16* __restrict__ B1s, __bf16* __restrict__ B2s,
                       const float* __restrict__ x, const int* __restrict__ perm,
                       __bf16* __restrict__ xp) {
  int b = blockIdx.x;
  if (b >= 3840) {  // ---- gather-convert part ----
    int tid = threadIdx.x;
    int p = (b - 3840) * 4 + (tid >> 6);
    int t = perm[p];
    __bf16* dst = xp + (long)p * HDIM;
    int c0 = (tid & 63) * 4;
    if (t < 0) {
      bf16x4 z = {};
#pragma unroll
      for (int it = 0; it < 4; ++it) *(bf16x4*)(dst + c0 + it * 256) = z;
    } else {
      const float* src = x + (long)t * HDIM;
#pragma unroll
      for (int it = 0; it < 4; ++it) {
        float4 v = *(const float4*)(src + c0 + it * 256);
        bf16x4 o = {(__bf16)v.x, (__bf16)v.y, (__bf16)v.z, (__bf16)v.w};
        *(bf16x4*)(dst + c0 + it * 256) = o;
      }
    }
    return;
  }
  // ---- transpose part: src [K][N] fp32 -> dst [rowmap(n)][K] bf16 ----
  const float* src;
  __bf16* dst;
  int K, N, interleave, slot, xt, yt;
  if (b < 2048) {  // gate_w/up_w -> B1r (16-col gate/up interleave)
    slot = b >> 10;
    int r = b & 1023, e = r >> 7, t = r & 127;
    xt = t & 7; yt = t >> 3;
    K = 1024; N = 512; interleave = 1;
    src = (slot ? uw : gw) + (long)e * (1024L * 512);
    dst = B1r + (long)e * (1024L * 1024);
  } else if (b < 3072) {  // down_w -> B2r
    int r = b - 2048, e = r >> 7, t = r & 127;
    xt = t & 15; yt = t >> 4;
    K = 512; N = 1024; interleave = 0; slot = 0;
    src = dw + (long)e * (512L * 1024);
    dst = B2r + (long)e * (1024L * 512);
  } else if (b < 3584) {  // shared gate/up -> B1s
    int r = b - 3072;
    slot = r >> 8;
    int t = r & 255;
    xt = t & 15; yt = t >> 4;
    K = 1024; N = 1024; interleave = 1;
    src = slot ? suw : sgw;
    dst = B1s;
  } else {  // shared down -> B2s
    int t = b - 3584;
    xt = t & 15; yt = t >> 4;
    K = 1024; N = 1024; interleave = 0; slot = 0;
    src = sdw;
    dst = B2s;
  }

  __shared__ float tile[64][65];
  int n0 = xt * 64, k0 = yt * 64;
  int tid = threadIdx.x, tx = tid & 15, ty = tid >> 4;
#pragma unroll
  for (int rr = 0; rr < 64; rr += 16) {
    float4 v = *(const float4*)(src + (long)(k0 + ty + rr) * N + n0 + tx * 4);
    tile[ty + rr][tx * 4 + 0] = v.x;
    tile[ty + rr][tx * 4 + 1] = v.y;
    tile[ty + rr][tx * 4 + 2] = v.z;
    tile[ty + rr][tx * 4 + 3] = v.w;
  }
  __syncthreads();
  int kp = tid & 31, rs = tid >> 5;
#pragma unroll
  for (int rr = 0; rr < 64; rr += 8) {
    int n = n0 + rs + rr;
    int row = interleave ? (((n >> 4) << 5) | (slot << 4) | (n & 15)) : n;
    bf16x2 u = {(__bf16)tile[2 * kp][rs + rr], (__bf16)tile[2 * kp + 1][rs + rr]};
    *(bf16x2*)(dst + (long)row * K + k0 + 2 * kp) = u;
  }
}

// ---------------- fused up-projection GEMM (shared + routed) ----------------
// R8: BK=64 — 16 K-steps (was 32). Staging: per wave 4 A + 4 B gl_lds16 per step,
// linear LDS dest, source chunk pre-swizzled with key=(row&7); ds_read chunk
// (ks*4+q)^(row&7) — same involution, 2 lanes/bank-quad (free). Fragments loaded
// per ks-slice to keep live set = 8 x bf16x8 (VGPR ~ unchanged -> 3 waves/SIMD).
__global__ __launch_bounds__(256) void k_up(
    const __bf16* __restrict__ A, const __bf16* __restrict__ B1s,
    const __bf16* __restrict__ B1r, __bf16* __restrict__ hs, __bf16* __restrict__ hr,
    const int* __restrict__ tileExpert, const int* __restrict__ numTiles) {
  int g = blockIdx.x;
  int s = g >> 3;
  int mTile = (s / 24) * 8 + (g & 7);
  int ny = s % 24;
  if (mTile >= *numTiles) return;
  bool sh = (ny < 16);
  const __bf16* Bb = sh ? (B1s + (long)ny * BN * 1024)
                        : (B1r + (long)tileExpert[mTile] * (1024L * 1024) +
                           (long)(ny - 16) * BN * 1024);

  __shared__ __attribute__((aligned(16))) __bf16 smem[BM * BK + BN * BK];  // 32 KB
  __bf16* As = smem;
  __bf16* Bs = smem + BM * BK;

  int tid = threadIdx.x, lane = tid & 63, wave = tid >> 6;
  int wRow = (wave >> 1) * 64, wCol = (wave & 1) * 64;
  int mBase = mTile * BM;

  int srow = lane >> 3;                // 0..7 : row offset within an 8-row stage slab
  int sch = (lane & 7) ^ srow;         // pre-swizzled source chunk (16B units)
  const __bf16* aSrc = A + (long)(mBase + wave * 32 + srow) * 1024 + sch * 8;
  const __bf16* bSrc = Bb + (long)(wave * 32 + srow) * 1024 + sch * 8;
  __bf16* aDst = &As[(wave * 32) * BK];
  __bf16* bDst = &Bs[(wave * 32) * BK];

  int m = lane & 15;
  int q = lane >> 4;
  int key = lane & 7;  // == (fragment row) & 7

  f32x4 acc[4][4] = {};
  for (int k0 = 0; k0 < 1024; k0 += BK) {
#pragma unroll
    for (int t = 0; t < 4; ++t) {
      gl_lds16(aSrc + k0 + t * (8 * 1024), aDst + t * (8 * BK));
      gl_lds16(bSrc + k0 + t * (8 * 1024), bDst + t * (8 * BK));
    }
    __syncthreads();
#pragma unroll
    for (int ks = 0; ks < 2; ++ks) {
      int ch = (ks * 4 + q) ^ key;
      bf16x8 af[4], bf[4];
#pragma unroll
      for (int i = 0; i < 4; ++i)
        af[i] = *(const bf16x8*)&As[(wRow + m + i * 16) * BK + ch * 8];
#pragma unroll
      for (int j = 0; j < 4; ++j)
        bf[j] = *(const bf16x8*)&Bs[(wCol + m + j * 16) * BK + ch * 8];
#pragma unroll
      for (int i = 0; i < 4; ++i)
#pragma unroll
        for (int j = 0; j < 4; ++j)
          acc[i][j] = __builtin_amdgcn_mfma_f32_16x16x32_bf16(af[i], bf[j], acc[i][j], 0, 0, 0);
    }
    __syncthreads();
  }

  // ---- R7 epilogue: SiLU*up -> wave-pair [64][64] LDS scratch -> 16B stores ----
  __bf16* scr = smem + (wave >> 1) * 4096;  // 64*64 bf16 per pair (fits in As region)
  int qq = lane >> 4, c = lane & 15;
  int w1 = (wave & 1) * 32;
#pragma unroll
  for (int i = 0; i < 4; ++i) {
#pragma unroll
    for (int jp = 0; jp < 2; ++jp) {
      f32x4 g2 = acc[i][2 * jp], u = acc[i][2 * jp + 1];
#pragma unroll
      for (int r = 0; r < 4; ++r) {
        float gv = g2[r];
        float sv = gv / (1.f + __expf(-gv)) * u[r];
        int lr = i * 16 + qq * 4 + r;  // (lr>>2)&3 == qq
        scr[lr * 64 + ((w1 + jp * 16 + c + qq * 16) & 63)] = (__bf16)sv;
      }
    }
  }
  __syncthreads();
  __bf16* dst = sh ? hs : hr;
  int ldh = sh ? 1024 : 512;
  int colBase = sh ? ny * 64 : (ny - 16) * 64;
  int rl = lane >> 3, chs = (lane & 7) * 8;
  long rowBase = mBase + (wave >> 1) * 64;
#pragma unroll
  for (int it = 0; it < 8; ++it) {
    int lr = rl + it * 8;
    bf16x8 v = *(const bf16x8*)&scr[lr * 64 + ((chs + ((lr >> 2) & 3) * 16) & 63)];
    *(bf16x8*)(dst + (rowBase + lr) * ldh + colBase + chs) = v;
  }
}

// ---------------- fused down-projection GEMM: out[perm[p]] = hs[p]*B2s + hr[p]*B2r[e] ----------------
__global__ __launch_bounds__(256) void k_down(
    const __bf16* __restrict__ hs, const __bf16* __restrict__ hr,
    const __bf16* __restrict__ B2s, const __bf16* __restrict__ B2r,
    float* __restrict__ out, const int* __restrict__ perm,
    const int* __restrict__ tileExpert, const int* __restrict__ numTiles) {
  int g = blockIdx.x;  // XCD swizzle (see k_up)
  int s = g >> 3;
  int mTile = (s / 8) * 8 + (g & 7);
  int nTile = s % 8;
  if (mTile >= *numTiles) return;
  int e = tileExpert[mTile];

  __shared__ __attribute__((aligned(16))) __bf16 smem[BM * BK + BN * BK];  // 32 KB
  __bf16* As = smem;
  __bf16* Bs = smem + BM * BK;

  int tid = threadIdx.x, lane = tid & 63, wave = tid >> 6;
  int wRow = (wave >> 1) * 64, wCol = (wave & 1) * 64;
  int mBase = mTile * BM;

  int srow = lane >> 3;
  int sch = (lane & 7) ^ srow;
  __bf16* aDst = &As[(wave * 32) * BK];
  __bf16* bDst = &Bs[(wave * 32) * BK];

  int m = lane & 15;
  int q = lane >> 4;
  int key = lane & 7;

  f32x4 acc[4][4] = {};

  // phase 1: shared down (K=1024, 16 steps)
  {
    const __bf16* aSrc = hs + (long)(mBase + wave * 32 + srow) * 1024 + sch * 8;
    const __bf16* bSrc = B2s + (long)(nTile * BN + wave * 32 + srow) * 1024 + sch * 8;
    for (int k0 = 0; k0 < 1024; k0 += BK) {
#pragma unroll
      for (int t = 0; t < 4; ++t) {
        gl_lds16(aSrc + k0 + t * (8 * 1024), aDst + t * (8 * BK));
        gl_lds16(bSrc + k0 + t * (8 * 1024), bDst + t * (8 * BK));
      }
      __syncthreads();
#pragma unroll
      for (int ks = 0; ks < 2; ++ks) {
        int ch = (ks * 4 + q) ^ key;
        bf16x8 af[4], bf[4];
#pragma unroll
        for (int i = 0; i < 4; ++i)
          af[i] = *(const bf16x8*)&As[(wRow + m + i * 16) * BK + ch * 8];
#pragma unroll
        for (int j = 0; j < 4; ++j)
          bf[j] = *(const bf16x8*)&Bs[(wCol + m + j * 16) * BK + ch * 8];
#pragma unroll
        for (int i = 0; i < 4; ++i)
#pragma unroll
          for (int j = 0; j < 4; ++j)
            acc[i][j] = __builtin_amdgcn_mfma_f32_16x16x32_bf16(af[i], bf[j], acc[i][j], 0, 0, 0);
      }
      __syncthreads();
    }
  }
  // phase 2: routed down (K=512, 8 steps)
  {
    const __bf16* aSrc = hr + (long)(mBase + wave * 32 + srow) * 512 + sch * 8;
    const __bf16* bSrc = B2r + (long)e * (1024L * 512) +
                         (long)(nTile * BN + wave * 32 + srow) * 512 + sch * 8;
    for (int k0 = 0; k0 < 512; k0 += BK) {
#pragma unroll
      for (int t = 0; t < 4; ++t) {
        gl_lds16(aSrc + k0 + t * (8 * 512), aDst + t * (8 * BK));
        gl_lds16(bSrc + k0 + t * (8 * 512), bDst + t * (8 * BK));
      }
      __syncthreads();
#pragma unroll
      for (int ks = 0; ks < 2; ++ks) {
        int ch = (ks * 4 + q) ^ key;
        bf16x8 af[4], bf[4];
#pragma unroll
        for (int i = 0; i < 4; ++i)
          af[i] = *(const bf16x8*)&As[(wRow + m + i * 16) * BK + ch * 8];
#pragma unroll
        for (int j = 0; j < 4; ++j)
          bf[j] = *(const bf16x8*)&Bs[(wCol + m + j * 16) * BK + ch * 8];
#pragma unroll
        for (int i = 0; i < 4; ++i)
#pragma unroll
          for (int j = 0; j < 4; ++j)
            acc[i][j] = __builtin_amdgcn_mfma_f32_16x16x32_bf16(af[i], bf[j], acc[i][j], 0, 0, 0);
      }
      __syncthreads();
    }
  }

  int qq = lane >> 4, c = lane & 15;
#pragma unroll
  for (int i = 0; i < 4; ++i) {
    int rowLoc = wRow + i * 16 + qq * 4;
#pragma unroll
    for (int r = 0; r < 4; ++r) {
      int tok = perm[mBase + rowLoc + r];
      if (tok >= 0) {
        float* op = out + (long)tok * 1024 + nTile * BN + wCol + c;
#pragma unroll
        for (int j = 0; j < 4; ++j) op[j * 16] = acc[i][j][r];
      }
    }
  }
}

// ---------------- launch ----------------
extern "C" void kernel_launch(void* const* d_in, const int* in_sizes, int n_in,
                              void* d_out, int out_size, void* d_ws, size_t ws_size,
                              hipStream_t stream) {
  const float* x = (const float*)d_in[0];
  const int* tok = (const int*)d_in[1];
  const float* gate_w = (const float*)d_in[2];
  const float* up_w = (const float*)d_in[3];
  const float* down_w = (const float*)d_in[4];
  const float* sgw = (const float*)d_in[5];
  const float* suw = (const float*)d_in[6];
  const float* sdw = (const float*)d_in[7];
  float* out = (float*)d_out;

  char* ws = (char*)d_ws;
  size_t off = 0;
  auto alloc = [&](size_t bytes) {
    void* p = ws + off;
    off = (off + bytes + 255) & ~(size_t)255;
    return p;
  };
  int* ctrl = (int*)alloc(1024);  // numTiles[1] tileExpert[136]
  int* numTiles = ctrl;
  int* tileExpert = ctrl + 8;
  int* perm = (int*)alloc((size_t)MPAD * 4);
  __bf16* xp = (__bf16*)alloc((size_t)MPAD * HDIM * 2);
  __bf16* B1r = (__bf16*)alloc((size_t)NEXPERTS * 1024 * 1024 * 2);  // gate|up interleaved
  __bf16* B2r = (__bf16*)alloc((size_t)NEXPERTS * 1024 * 512 * 2);
  __bf16* B1s = (__bf16*)alloc((size_t)2048 * 1024 * 2);
  __bf16* B2s = (__bf16*)alloc((size_t)1024 * 1024 * 2);
  __bf16* hs = (__bf16*)alloc((size_t)MPAD * 1024 * 2);
  __bf16* hr = (__bf16*)alloc((size_t)MPAD * 512 * 2);
  (void)ws_size;  // ~121 MB used

  k_route<<<1, 1024, 0, stream>>>(tok, perm, tileExpert, numTiles);
  k_prep<<<3840 + MPAD / 4, 256, 0, stream>>>(gate_w, up_w, down_w, sgw, suw, sdw, B1r, B2r,
                                              B1s, B2s, x, perm, xp);
  k_up<<<MAX_TILES * 24, 256, 0, stream>>>(xp, B1s, B1r, hs, hr, tileExpert, numTiles);
  k_down<<<MAX_TILES * 8, 256, 0, stream>>>(hs, hr, B2s, B2r, out, perm, tileExpert,
                                            numTiles);
}